// Round 1
// baseline (95.064 us; speedup 1.0000x reference)
//
#include <hip/hip_runtime.h>
#include <stdint.h>

#define NN 8192
#define DD 512
#define BM 128
#define BK 64
#define LDK 72            // padded LDS row stride in bf16 (144 B): conflict-free b128 r/w
#define NB 64             // NN / BM
#define NTILES 2080       // NB*(NB+1)/2 upper-triangular tiles

typedef short s16x8 __attribute__((ext_vector_type(8)));
typedef float f32x4 __attribute__((ext_vector_type(4)));

static __device__ __forceinline__ short f2bf(float x) {
  union { float f; uint32_t u; } c; c.f = x;
  uint32_t r = c.u + 0x7fffu + ((c.u >> 16) & 1u);   // RNE
  return (short)(r >> 16);
}

static __device__ __forceinline__ int tri_off(int b) {
  return b * NB - (b * (b - 1)) / 2;
}

// One block (1 wave) per row: fp32 -> bf16 convert, sq-norm in fp32, init reductions.
__global__ __launch_bounds__(64) void prep_kernel(
    const float* __restrict__ f, short* __restrict__ fb,
    float* __restrict__ sqn, float* __restrict__ pmax,
    float* __restrict__ nmin, float* __restrict__ rmax) {
  int row = blockIdx.x;
  int lane = threadIdx.x;
  const float4* src = (const float4*)(f + (size_t)row * DD);
  float4 v0 = src[lane * 2];
  float4 v1 = src[lane * 2 + 1];
  float s = v0.x*v0.x + v0.y*v0.y + v0.z*v0.z + v0.w*v0.w
          + v1.x*v1.x + v1.y*v1.y + v1.z*v1.z + v1.w*v1.w;
  s16x8 o;
  o[0]=f2bf(v0.x); o[1]=f2bf(v0.y); o[2]=f2bf(v0.z); o[3]=f2bf(v0.w);
  o[4]=f2bf(v1.x); o[5]=f2bf(v1.y); o[6]=f2bf(v1.z); o[7]=f2bf(v1.w);
  *(s16x8*)&fb[(size_t)row * DD + lane * 8] = o;
  #pragma unroll
  for (int m = 1; m < 64; m <<= 1) s += __shfl_xor(s, m);
  if (lane == 0) {
    sqn[row] = s;
    pmax[row] = 0.f;
    nmin[row] = __int_as_float(0x7f800000);   // +inf
    rmax[row] = 0.f;
  }
}

// Upper-triangular 128x128 tiles of F*F^T via bf16 MFMA; fused masked reductions
// for both the tile's rows and its columns (symmetry).
__global__ __launch_bounds__(256, 2) void tile_kernel(
    const short* __restrict__ fb, const float* __restrict__ sqn,
    const int* __restrict__ lab,
    float* __restrict__ pmax, float* __restrict__ nmin, float* __restrict__ rmax) {
  __shared__ __align__(16) short As[BM * LDK];
  __shared__ __align__(16) short Bs[BM * LDK];
  __shared__ float s_sq_r[BM], s_sq_c[BM];
  __shared__ int   s_lb_r[BM], s_lb_c[BM];

  // XCD-aware swizzle (2080 % 8 == 0) then linear -> (bi,bj) upper-tri decode
  int t0 = blockIdx.x;
  int t = (t0 & 7) * (NTILES / 8) + (t0 >> 3);
  int bi = (int)((129.0f - sqrtf(16641.0f - 8.0f * (float)t)) * 0.5f);
  if (bi < 0) bi = 0;
  while (bi > 0 && tri_off(bi) > t) --bi;
  while (tri_off(bi + 1) <= t) ++bi;
  int bj = bi + (t - tri_off(bi));
  int brow = bi * BM, bcol = bj * BM;

  int tid = threadIdx.x;
  int wid = tid >> 6, lane = tid & 63;
  int hi = lane >> 4, lo = lane & 15;

  if (tid < BM) {
    s_sq_r[tid] = sqn[brow + tid];
    s_lb_r[tid] = lab[brow + tid];
    s_sq_c[tid] = sqn[bcol + tid];
    s_lb_c[tid] = lab[bcol + tid];
  }

  f32x4 acc[2][8];
  #pragma unroll
  for (int a = 0; a < 2; ++a)
    #pragma unroll
    for (int b = 0; b < 8; ++b) acc[a][b] = (f32x4)(0.f);

  int r0 = tid >> 3, sg = tid & 7;

  for (int kt = 0; kt < DD / BK; ++kt) {
    // prefetch to regs (global only, no LDS dep)
    s16x8 ra[4], rb[4];
    size_t kb = (size_t)kt * BK + sg * 8;
    #pragma unroll
    for (int it = 0; it < 4; ++it) {
      int row = it * 32 + r0;
      ra[it] = *(const s16x8*)&fb[(size_t)(brow + row) * DD + kb];
      rb[it] = *(const s16x8*)&fb[(size_t)(bcol + row) * DD + kb];
    }
    __syncthreads();   // prior tile's compute done
    #pragma unroll
    for (int it = 0; it < 4; ++it) {
      int row = it * 32 + r0;
      *(s16x8*)&As[row * LDK + sg * 8] = ra[it];
      *(s16x8*)&Bs[row * LDK + sg * 8] = rb[it];
    }
    __syncthreads();   // staging visible
    #pragma unroll
    for (int ks = 0; ks < 2; ++ks) {
      int ko = ks * 32 + hi * 8;
      s16x8 a0 = *(const s16x8*)&As[(wid * 32 + lo) * LDK + ko];
      s16x8 a1 = *(const s16x8*)&As[(wid * 32 + 16 + lo) * LDK + ko];
      s16x8 bfr[8];
      #pragma unroll
      for (int fc = 0; fc < 8; ++fc)
        bfr[fc] = *(const s16x8*)&Bs[(fc * 16 + lo) * LDK + ko];
      #pragma unroll
      for (int fc = 0; fc < 8; ++fc) {
        acc[0][fc] = __builtin_amdgcn_mfma_f32_16x16x32_bf16(a0, bfr[fc], acc[0][fc], 0, 0, 0);
        acc[1][fc] = __builtin_amdgcn_mfma_f32_16x16x32_bf16(a1, bfr[fc], acc[1][fc], 0, 0, 0);
      }
    }
  }

  // Epilogue: pdist + masked reductions (rows and, by symmetry, columns).
  const float FINF = __int_as_float(0x7f800000);
  float cvp[8], cvn[8], cvr[8];
  #pragma unroll
  for (int fc = 0; fc < 8; ++fc) { cvp[fc] = 0.f; cvn[fc] = FINF; cvr[fc] = 0.f; }

  #pragma unroll
  for (int fr = 0; fr < 2; ++fr) {
    #pragma unroll
    for (int rg = 0; rg < 4; ++rg) {
      int rt = wid * 32 + fr * 16 + hi * 4 + rg;
      int gi = brow + rt;
      float sqi = s_sq_r[rt];
      int   li  = s_lb_r[rt];
      float vp = 0.f, vn = FINF, vr = 0.f;
      #pragma unroll
      for (int fc = 0; fc < 8; ++fc) {
        int ct = fc * 16 + lo;
        int gj = bcol + ct;
        float g  = acc[fr][fc][rg];
        float sq = sqi + s_sq_c[ct] - 2.0f * g;
        float d  = (sq > 0.f) ? sqrtf(sq) : 0.f;
        if (gi == gj) d = 0.f;
        bool same = (li == s_lb_c[ct]);
        vr = fmaxf(vr, d);
        cvr[fc] = fmaxf(cvr[fc], d);
        if (same) {
          float dp = (gi == gj) ? 0.f : d;
          vp = fmaxf(vp, dp);
          cvp[fc] = fmaxf(cvp[fc], dp);
        } else {
          vn = fminf(vn, d);
          cvn[fc] = fminf(cvn[fc], d);
        }
      }
      // reduce across the 16 lanes sharing this row (cols)
      #pragma unroll
      for (int m = 1; m < 16; m <<= 1) {
        vr = fmaxf(vr, __shfl_xor(vr, m));
        vp = fmaxf(vp, __shfl_xor(vp, m));
        vn = fminf(vn, __shfl_xor(vn, m));
      }
      if (lo == 0) {
        atomicMax((int*)&rmax[gi], __float_as_int(vr));
        atomicMax((int*)&pmax[gi], __float_as_int(vp));
        atomicMin((int*)&nmin[gi], __float_as_int(vn));
      }
    }
  }
  // column-side reduction: combine across hi groups (rows), then atomics
  #pragma unroll
  for (int fc = 0; fc < 8; ++fc) {
    #pragma unroll
    for (int m = 16; m < 64; m <<= 1) {
      cvr[fc] = fmaxf(cvr[fc], __shfl_xor(cvr[fc], m));
      cvp[fc] = fmaxf(cvp[fc], __shfl_xor(cvp[fc], m));
      cvn[fc] = fminf(cvn[fc], __shfl_xor(cvn[fc], m));
    }
    if (hi == 0) {
      int gj = bcol + fc * 16 + lo;
      atomicMax((int*)&rmax[gj], __float_as_int(cvr[fc]));
      atomicMax((int*)&pmax[gj], __float_as_int(cvp[fc]));
      atomicMin((int*)&nmin[gj], __float_as_int(cvn[fc]));
    }
  }
}

__global__ __launch_bounds__(256) void finalize_kernel(
    const float* __restrict__ pmax, const float* __restrict__ nmin,
    const float* __restrict__ rmax, float* __restrict__ out) {
  int i = blockIdx.x * blockDim.x + threadIdx.x;
  if (i < NN) {
    out[2 * i]     = pmax[i];
    out[2 * i + 1] = fminf(nmin[i], rmax[i]);   // no-negative fallback = axis_max
  }
}

extern "C" void kernel_launch(void* const* d_in, const int* in_sizes, int n_in,
                              void* d_out, int out_size, void* d_ws, size_t ws_size,
                              hipStream_t stream) {
  const float* feat = (const float*)d_in[0];
  const int*   lab  = (const int*)d_in[1];
  float* out = (float*)d_out;

  char* ws = (char*)d_ws;
  short* fb   = (short*)ws;                                  // 8192*512*2 = 8388608 B
  float* sqn  = (float*)(ws + 8388608);                      // 32768 B
  float* pmax = (float*)(ws + 8388608 + 32768);              // 32768 B
  float* nmin = (float*)(ws + 8388608 + 2 * 32768);          // 32768 B
  float* rmax = (float*)(ws + 8388608 + 3 * 32768);          // 32768 B

  prep_kernel<<<NN, 64, 0, stream>>>(feat, fb, sqn, pmax, nmin, rmax);
  tile_kernel<<<NTILES, 256, 0, stream>>>(fb, sqn, lab, pmax, nmin, rmax);
  finalize_kernel<<<(NN + 255) / 256, 256, 0, stream>>>(pmax, nmin, rmax, out);
}

// Round 2
// 95.024 us; speedup vs baseline: 1.0004x; 1.0004x over previous
//
#include <hip/hip_runtime.h>
#include <stdint.h>

#define NN 8192
#define DD 512
#define BM 128
#define BK 64             // bf16 elements per K-step = 128 B rows in LDS
#define NB 64             // NN / BM
#define NTILES 2080       // NB*(NB+1)/2 upper-triangular tiles

typedef short s16x8 __attribute__((ext_vector_type(8)));
typedef float f32x4 __attribute__((ext_vector_type(4)));

static __device__ __forceinline__ short f2bf(float x) {
  union { float f; uint32_t u; } c; c.f = x;
  uint32_t r = c.u + 0x7fffu + ((c.u >> 16) & 1u);   // RNE
  return (short)(r >> 16);
}

static __device__ __forceinline__ int tri_off(int b) {
  return b * NB - (b * (b - 1)) / 2;
}

static __device__ __forceinline__ void gload16(const void* g, void* l) {
  __builtin_amdgcn_global_load_lds(
      (const __attribute__((address_space(1))) void*)g,
      (__attribute__((address_space(3))) void*)l, 16, 0, 0);
}

// 4 waves/block, one row per wave: fp32 -> bf16, sq-norm, init reductions.
__global__ __launch_bounds__(256) void prep_kernel(
    const float* __restrict__ f, short* __restrict__ fb,
    float* __restrict__ sqn, float* __restrict__ pmax,
    float* __restrict__ nmin, float* __restrict__ rmax) {
  int wid = threadIdx.x >> 6, lane = threadIdx.x & 63;
  int row = blockIdx.x * 4 + wid;
  const float4* src = (const float4*)(f + (size_t)row * DD);
  float4 v0 = src[lane * 2];
  float4 v1 = src[lane * 2 + 1];
  float s = v0.x*v0.x + v0.y*v0.y + v0.z*v0.z + v0.w*v0.w
          + v1.x*v1.x + v1.y*v1.y + v1.z*v1.z + v1.w*v1.w;
  s16x8 o;
  o[0]=f2bf(v0.x); o[1]=f2bf(v0.y); o[2]=f2bf(v0.z); o[3]=f2bf(v0.w);
  o[4]=f2bf(v1.x); o[5]=f2bf(v1.y); o[6]=f2bf(v1.z); o[7]=f2bf(v1.w);
  *(s16x8*)&fb[(size_t)row * DD + lane * 8] = o;
  #pragma unroll
  for (int m = 1; m < 64; m <<= 1) s += __shfl_xor(s, m);
  if (lane == 0) {
    sqn[row] = s;
    pmax[row] = 0.f;
    nmin[row] = __int_as_float(0x7f800000);   // +inf
    rmax[row] = 0.f;
  }
}

// Upper-triangular 128x128 tiles of F*F^T via bf16 MFMA + global_load_lds
// staging (linear LDS dest, swizzled global source + swizzled ds_read).
__global__ __launch_bounds__(256, 3) void tile_kernel(
    const short* __restrict__ fb, const float* __restrict__ sqn,
    const int* __restrict__ lab,
    float* __restrict__ pmax, float* __restrict__ nmin, float* __restrict__ rmax) {
  __shared__ __align__(16) short As[BM * 64];   // 16 KB, linear [row][64]
  __shared__ __align__(16) short Bs[BM * 64];   // 16 KB
  __shared__ float s_sq_r[BM], s_sq_c[BM];
  __shared__ int   s_lb_r[BM], s_lb_c[BM];
  __shared__ float colred[3][4][BM];            // 6 KB cross-wave col combine

  // XCD-aware swizzle (2080 % 8 == 0, bijective) then upper-tri decode
  int t0 = blockIdx.x;
  int t = (t0 & 7) * (NTILES / 8) + (t0 >> 3);
  int bi = (int)((129.0f - sqrtf(16641.0f - 8.0f * (float)t)) * 0.5f);
  if (bi < 0) bi = 0;
  while (bi > 0 && tri_off(bi) > t) --bi;
  while (tri_off(bi + 1) <= t) ++bi;
  int bj = bi + (t - tri_off(bi));
  int brow = bi * BM, bcol = bj * BM;

  int tid = threadIdx.x;
  int wid = tid >> 6, lane = tid & 63;
  int hi = lane >> 4, lo = lane & 15;

  if (tid < BM) {
    s_sq_r[tid] = sqn[brow + tid];
    s_lb_r[tid] = lab[brow + tid];
    s_sq_c[tid] = sqn[bcol + tid];
    s_lb_c[tid] = lab[bcol + tid];
  }

  f32x4 acc[2][8];
  #pragma unroll
  for (int a = 0; a < 2; ++a)
    #pragma unroll
    for (int b = 0; b < 8; ++b) acc[a][b] = (f32x4)(0.f);

  // staging lane constants: lane covers row (seg*8 + lane>>3), 16B chunk
  // (lane&7) of that row, fetched from global chunk ((lane&7) ^ (row&7))
  // so LDS[row][p] = G[row][p ^ (row&7)]  (both-sides swizzle, linear dest)
  int lrow = lane >> 3;
  int lchunk = (lane & 7) ^ lrow;
  size_t lane_goff = (size_t)lrow * DD + lchunk * 8;   // shorts
  const short* gA = fb + (size_t)brow * DD + lane_goff;
  const short* gB = fb + (size_t)bcol * DD + lane_goff;

  // read-side swizzled chunk: want G[row][C], C = ks*4+hi; row&7 == lo&7
  // for every A/B fragment row -> chunk = C ^ (lo&7), uniform per lane
  int cs0 = hi ^ (lo & 7);          // ks=0
  int cs1 = cs0 ^ 4;                // ks=1

  for (int kt = 0; kt < DD / BK; ++kt) {
    __syncthreads();   // prior tile's ds_reads done (and initial LDS fills)
    int kb = kt * BK;  // shorts
    #pragma unroll
    for (int i = 0; i < 4; ++i) {
      int seg = wid * 4 + i;
      gload16(gA + (size_t)seg * 8 * DD + kb, &As[seg * 512]);
      gload16(gB + (size_t)seg * 8 * DD + kb, &Bs[seg * 512]);
    }
    __syncthreads();   // staging visible (compiler drains vmcnt at barrier)
    #pragma unroll
    for (int ks = 0; ks < 2; ++ks) {
      int cs = ks ? cs1 : cs0;
      int a0r = wid * 32 + lo;
      s16x8 a0 = *(const s16x8*)&As[a0r * 64 + cs * 8];
      s16x8 a1 = *(const s16x8*)&As[(a0r + 16) * 64 + cs * 8];
      s16x8 bfr[8];
      #pragma unroll
      for (int fc = 0; fc < 8; ++fc)
        bfr[fc] = *(const s16x8*)&Bs[(fc * 16 + lo) * 64 + cs * 8];
      #pragma unroll
      for (int fc = 0; fc < 8; ++fc) {
        acc[0][fc] = __builtin_amdgcn_mfma_f32_16x16x32_bf16(a0, bfr[fc], acc[0][fc], 0, 0, 0);
        acc[1][fc] = __builtin_amdgcn_mfma_f32_16x16x32_bf16(a1, bfr[fc], acc[1][fc], 0, 0, 0);
      }
    }
  }

  // Epilogue: pdist + masked reductions (rows and, by symmetry, columns).
  const float FINF = __int_as_float(0x7f800000);
  float cvp[8], cvn[8], cvr[8];
  #pragma unroll
  for (int fc = 0; fc < 8; ++fc) { cvp[fc] = 0.f; cvn[fc] = FINF; cvr[fc] = 0.f; }

  #pragma unroll
  for (int fr = 0; fr < 2; ++fr) {
    #pragma unroll
    for (int rg = 0; rg < 4; ++rg) {
      int rt = wid * 32 + fr * 16 + hi * 4 + rg;
      int gi = brow + rt;
      float sqi = s_sq_r[rt];
      int   li  = s_lb_r[rt];
      float vp = 0.f, vn = FINF, vr = 0.f;
      #pragma unroll
      for (int fc = 0; fc < 8; ++fc) {
        int ct = fc * 16 + lo;
        int gj = bcol + ct;
        float g  = acc[fr][fc][rg];
        float sq = sqi + s_sq_c[ct] - 2.0f * g;
        float d  = (sq > 0.f) ? sqrtf(sq) : 0.f;
        if (gi == gj) d = 0.f;
        bool same = (li == s_lb_c[ct]);
        vr = fmaxf(vr, d);
        cvr[fc] = fmaxf(cvr[fc], d);
        if (same) {
          vp = fmaxf(vp, d);
          cvp[fc] = fmaxf(cvp[fc], d);
        } else {
          vn = fminf(vn, d);
          cvn[fc] = fminf(cvn[fc], d);
        }
      }
      // reduce across the 16 lanes sharing this row (cols)
      #pragma unroll
      for (int m = 1; m < 16; m <<= 1) {
        vr = fmaxf(vr, __shfl_xor(vr, m));
        vp = fmaxf(vp, __shfl_xor(vp, m));
        vn = fminf(vn, __shfl_xor(vn, m));
      }
      if (lo == 0) {
        atomicMax((int*)&rmax[gi], __float_as_int(vr));
        atomicMax((int*)&pmax[gi], __float_as_int(vp));
        atomicMin((int*)&nmin[gi], __float_as_int(vn));
      }
    }
  }
  // column-side: combine across hi groups (rows) in-wave, then cross-wave via LDS
  #pragma unroll
  for (int fc = 0; fc < 8; ++fc) {
    #pragma unroll
    for (int m = 16; m < 64; m <<= 1) {
      cvr[fc] = fmaxf(cvr[fc], __shfl_xor(cvr[fc], m));
      cvp[fc] = fmaxf(cvp[fc], __shfl_xor(cvp[fc], m));
      cvn[fc] = fminf(cvn[fc], __shfl_xor(cvn[fc], m));
    }
    if (hi == 0) {
      int ct = fc * 16 + lo;
      colred[0][wid][ct] = cvp[fc];
      colred[1][wid][ct] = cvn[fc];
      colred[2][wid][ct] = cvr[fc];
    }
  }
  __syncthreads();
  if (tid < BM) {
    float p = colred[0][0][tid], n = colred[1][0][tid], r = colred[2][0][tid];
    #pragma unroll
    for (int w = 1; w < 4; ++w) {
      p = fmaxf(p, colred[0][w][tid]);
      n = fminf(n, colred[1][w][tid]);
      r = fmaxf(r, colred[2][w][tid]);
    }
    int gj = bcol + tid;
    atomicMax((int*)&pmax[gj], __float_as_int(p));
    atomicMin((int*)&nmin[gj], __float_as_int(n));
    atomicMax((int*)&rmax[gj], __float_as_int(r));
  }
}

__global__ __launch_bounds__(256) void finalize_kernel(
    const float* __restrict__ pmax, const float* __restrict__ nmin,
    const float* __restrict__ rmax, float* __restrict__ out) {
  int i = blockIdx.x * blockDim.x + threadIdx.x;
  if (i < NN) {
    out[2 * i]     = pmax[i];
    out[2 * i + 1] = fminf(nmin[i], rmax[i]);   // no-negative fallback = axis_max
  }
}

extern "C" void kernel_launch(void* const* d_in, const int* in_sizes, int n_in,
                              void* d_out, int out_size, void* d_ws, size_t ws_size,
                              hipStream_t stream) {
  const float* feat = (const float*)d_in[0];
  const int*   lab  = (const int*)d_in[1];
  float* out = (float*)d_out;

  char* ws = (char*)d_ws;
  short* fb   = (short*)ws;                                  // 8192*512*2 = 8388608 B
  float* sqn  = (float*)(ws + 8388608);                      // 32768 B
  float* pmax = (float*)(ws + 8388608 + 32768);              // 32768 B
  float* nmin = (float*)(ws + 8388608 + 2 * 32768);          // 32768 B
  float* rmax = (float*)(ws + 8388608 + 3 * 32768);          // 32768 B

  prep_kernel<<<NN / 4, 256, 0, stream>>>(feat, fb, sqn, pmax, nmin, rmax);
  tile_kernel<<<NTILES, 256, 0, stream>>>(fb, sqn, lab, pmax, nmin, rmax);
  finalize_kernel<<<(NN + 255) / 256, 256, 0, stream>>>(pmax, nmin, rmax, out);
}